// Round 12
// baseline (416.826 us; speedup 1.0000x reference)
//
#include <hip/hip_runtime.h>
#include <cfloat>
#include <climits>
#include <math.h>

#define BN 16
#define QN 4096
#define GN 256
#define CN 80
#define NPART 128          // row parts in k_main (32 rows each)
#define RPP (QN / NPART)   // 32
#define NPRM 23            // column params

typedef unsigned long long u64;

__device__ __forceinline__ bool lexLessF(float a, int ia, float b, int ib) {
    return (a < b) || (a == b && ia < ib);
}
// IEEE order-isomorphic u32 key (no NaNs in this data)
__device__ __forceinline__ unsigned int fkey(float f) {
    unsigned int b = __float_as_uint(f);
    return b ^ ((b >> 31) ? 0xFFFFFFFFu : 0x80000000u);
}
__device__ __forceinline__ float funkey(unsigned int k) {
    unsigned int b = k ^ ((k >> 31) ? 0x80000000u : 0xFFFFFFFFu);
    return __uint_as_float(b);
}

// ---------------- zero init (rowmask + colcnt + staleCount) ----------------
__global__ void k_zero(u64* __restrict__ p, int n) {
    int i = blockIdx.x * blockDim.x + threadIdx.x;
    if (i < n) p[i] = 0ull;
}

// ---------------- focal class-cost table (TRANSPOSED [b][i][c]) + prmT ----------------
__global__ __launch_bounds__(256) void k_class(const float* __restrict__ logits,
                                               const float* __restrict__ gtb,
                                               const float* __restrict__ gtt,
                                               const float* __restrict__ gtr,
                                               const float* __restrict__ imgt,
                                               float* __restrict__ cclsT,
                                               float* __restrict__ prmT) {
#pragma clang fp contract(off)
    const int b = blockIdx.x >> 6, iblk = blockIdx.x & 63;
    const int lane = threadIdx.x & 63, cg = threadIdx.x >> 6;  // 4 c-groups x 20
    const int i = iblk * 64 + lane;
    const float* lrow = logits + ((size_t)(b * QN + i)) * CN + cg * 20;
    float* orow = cclsT + ((size_t)(b * QN + i)) * CN + cg * 20;
#pragma unroll
    for (int q = 0; q < 5; q++) {
        const float4 xv = *reinterpret_cast<const float4*>(lrow + q * 4);
        float xs[4] = {xv.x, xv.y, xv.z, xv.w};
        float os[4];
#pragma unroll
        for (int u = 0; u < 4; u++) {
            float x = xs[u];
            float e = (float)exp(-(double)x);
            float pr = 1.0f / (1.0f + e);
            float om = 1.0f - pr;
            float lneg = (float)log((double)(om + 1e-8f));
            float lpos = (float)log((double)(pr + 1e-8f));
            float neg = (0.75f * (pr * pr)) * (-lneg);
            float pos = (0.25f * (om * om)) * (-lpos);
            os[u] = pos - neg;
        }
        *reinterpret_cast<float4*>(orow + q * 4) = make_float4(os[0], os[1], os[2], os[3]);
    }
    if (iblk == 0) {
        const int j = threadIdx.x;
        const float* g = gtb + ((size_t)(b * GN + j)) * 4;
        const float g0 = g[0], g1 = g[1], g2 = g[2], g3 = g[3];
        const float* it = imgt + ((size_t)(b * GN + j)) * 4;
        float* P = prmT + (size_t)b * NPRM * GN;
        P[0 * GN + j] = g0; P[1 * GN + j] = g1; P[2 * GN + j] = g2; P[3 * GN + j] = g3;
        P[4 * GN + j] = g0 / it[0]; P[5 * GN + j] = g1 / it[1];
        P[6 * GN + j] = g2 / it[2]; P[7 * GN + j] = g3 / it[3];
        P[8 * GN + j] = gtt[(b * GN + j) * 3 + 0]; P[9 * GN + j] = gtt[(b * GN + j) * 3 + 1];
        P[10 * GN + j] = gtt[(b * GN + j) * 3 + 2];
        P[11 * GN + j] = gtr[(b * GN + j) * 3 + 0]; P[12 * GN + j] = gtr[(b * GN + j) * 3 + 1];
        P[13 * GN + j] = gtr[(b * GN + j) * 3 + 2];
        P[14 * GN + j] = (g2 - g0) * (g3 - g1);   // ga
        float gcx = (g0 + g2) * 0.5f, gcy = (g1 + g3) * 0.5f;
        float gw = g2 - g0, gh = g3 - g1;
        float X0 = gcx - gw * 0.5f, Y0 = gcy - gh * 0.5f;
        float X1 = gcx + gw * 0.5f, Y1 = gcy + gh * 0.5f;
        float Wd = X1 - X0, Hd = Y1 - Y0;
        P[15 * GN + j] = X0; P[16 * GN + j] = Y0; P[17 * GN + j] = X1; P[18 * GN + j] = Y1;
        P[19 * GN + j] = gcx - 2.5f * Wd; P[20 * GN + j] = gcx + 2.5f * Wd;
        P[21 * GN + j] = gcy - 2.5f * Hd; P[22 * GN + j] = gcy + 2.5f * Hd;
    }
}

// ---------------- fg per query row, 4-way j-split ----------------
__global__ __launch_bounds__(256) void k_fg(const float* __restrict__ gtb,
                                            const float* __restrict__ pb,
                                            unsigned char* __restrict__ fgp) {
#pragma clang fp contract(off)
    const int b = blockIdx.y;
    const int part = blockIdx.z;
    const int i = blockIdx.x * 256 + threadIdx.x;
    __shared__ float s[64][8];
    if (threadIdx.x < 64) {
        const int j = part * 64 + threadIdx.x;
        const float* g = gtb + ((size_t)(b * GN + j)) * 4;
        float g0 = g[0], g1 = g[1], g2 = g[2], g3 = g[3];
        float gcx = (g0 + g2) * 0.5f, gcy = (g1 + g3) * 0.5f;
        float gw = g2 - g0, gh = g3 - g1;
        float x0 = gcx - gw * 0.5f, y0 = gcy - gh * 0.5f;
        float x1 = gcx + gw * 0.5f, y1 = gcy + gh * 0.5f;
        float w = x1 - x0, h = y1 - y0;
        s[threadIdx.x][0] = x0; s[threadIdx.x][1] = y0; s[threadIdx.x][2] = x1; s[threadIdx.x][3] = y1;
        s[threadIdx.x][4] = gcx - 2.5f * w; s[threadIdx.x][5] = gcx + 2.5f * w;
        s[threadIdx.x][6] = gcy - 2.5f * h; s[threadIdx.x][7] = gcy + 2.5f * h;
    }
    __syncthreads();
    const float4 bb = *reinterpret_cast<const float4*>(pb + ((size_t)(b * QN + i)) * 4);
    float ax = (bb.x + bb.z) * 0.5f, ay = (bb.y + bb.w) * 0.5f;
    bool anyib = false, anyic = false;
#pragma unroll 8
    for (int j = 0; j < 64; j++) {
        bool ib = (ax > s[j][0]) && (ax < s[j][2]) && (ay > s[j][1]) && (ay < s[j][3]);
        bool ic = (ax > s[j][4]) && (ax < s[j][5]) && (ay > s[j][6]) && (ay < s[j][7]);
        anyib |= ib; anyic |= ic;
    }
    fgp[((size_t)b * QN + i) * 4 + part] = (anyib || anyic) ? 1 : 0;
}

// ---------------- per-row common table rowp[b][i][20] ----------------
__global__ __launch_bounds__(256) void k_rows(const float* __restrict__ pboxes,
                                              const float* __restrict__ pposes,
                                              const float* __restrict__ img,
                                              const unsigned int* __restrict__ fgw,
                                              float* __restrict__ rowp) {
#pragma clang fp contract(off)
    const int b = blockIdx.y;
    const int i = blockIdx.x * 256 + threadIdx.x;
    const float im0 = img[b * 4 + 0], im1 = img[b * 4 + 1], im2 = img[b * 4 + 2], im3 = img[b * 4 + 3];
    const float4 bx = *reinterpret_cast<const float4*>(pboxes + ((size_t)(b * QN + i)) * 4);
    const float b0 = bx.x, b1 = bx.y, b2 = bx.z, b3 = bx.w;
    const float2* pp2 = reinterpret_cast<const float2*>(pposes + ((size_t)(b * QN + i)) * 6);
    const float2 q0 = pp2[0], q1 = pp2[1], q2 = pp2[2];
    const float fgadd = fgw[(size_t)b * QN + i] ? 0.0f : 10000.0f;
    const float bn0 = b0 / im0, bn1 = b1 / im1, bn2 = b2 / im2, bn3 = b3 / im3;
    const float a1 = (b2 - b0) * (b3 - b1);
    const float ax = (b0 + b2) * 0.5f, ay = (b1 + b3) * 0.5f;
    float4* R = reinterpret_cast<float4*>(rowp + ((size_t)(b * QN) + i) * 20);
    R[0] = make_float4(b0, b1, b2, b3);
    R[1] = make_float4(bn0, bn1, bn2, bn3);
    R[2] = make_float4(ax, ay, a1, fgadd);
    R[3] = make_float4(q0.x, q0.y, q1.x, q1.y);
    R[4] = make_float4(q2.x, q2.y, 0.0f, 0.0f);
}

// ---------------- fused cost + selection: column-per-thread, u64 keys ----------------
__global__ __launch_bounds__(256) void k_main(
    const float* __restrict__ cclsT, const int* __restrict__ labels,
    const float* __restrict__ prmT, const float* __restrict__ rowp,
    float* __restrict__ costT,
    u64* __restrict__ pck, float* __restrict__ piv) {
#pragma clang fp contract(off)
    const int j = threadIdx.x;
    const int b = blockIdx.x >> 7;
    const int part = blockIdx.x & 127;
    const int i0 = part * RPP;
    const float* P = prmT + (size_t)b * NPRM * GN;
    const float g0 = P[0 * GN + j], g1 = P[1 * GN + j], g2 = P[2 * GN + j], g3 = P[3 * GN + j];
    const float gn0 = P[4 * GN + j], gn1 = P[5 * GN + j], gn2 = P[6 * GN + j], gn3 = P[7 * GN + j];
    const float t0 = P[8 * GN + j], t1 = P[9 * GN + j], t2 = P[10 * GN + j];
    const float r0 = P[11 * GN + j], r1 = P[12 * GN + j], r2 = P[13 * GN + j];
    const float ga = P[14 * GN + j];
    const float X0 = P[15 * GN + j], Y0 = P[16 * GN + j], X1 = P[17 * GN + j], Y1 = P[18 * GN + j];
    const float LOX = P[19 * GN + j], HIX = P[20 * GN + j], LOY = P[21 * GN + j], HIY = P[22 * GN + j];
    const int lab = labels[b * GN + j];

    const float* RB = rowp + ((size_t)(b * QN) + i0) * 20;      // uniform base
    const float* CB = cclsT + ((size_t)(b * QN) + i0) * CN;     // uniform base + lab
    float* CT = costT + ((size_t)(b * QN) + i0) * GN + j;

    u64 ck[5]; float iv[5];
#pragma unroll
    for (int k = 0; k < 5; k++) { ck[k] = ~0ull; iv[k] = -1.0f; }

    for (int r = 0; r < RPP; r++) {
        const int i = i0 + r;
        const float4 R0 = *reinterpret_cast<const float4*>(RB + r * 20 + 0);   // uniform -> s_load
        const float4 R1 = *reinterpret_cast<const float4*>(RB + r * 20 + 4);
        const float4 R2 = *reinterpret_cast<const float4*>(RB + r * 20 + 8);
        const float4 R3 = *reinterpret_cast<const float4*>(RB + r * 20 + 12);
        const float4 R4 = *reinterpret_cast<const float4*>(RB + r * 20 + 16);
        const float b0 = R0.x, b1 = R0.y, b2 = R0.z, b3 = R0.w;
        const float bn0 = R1.x, bn1 = R1.y, bn2 = R1.z, bn3 = R1.w;
        const float ax = R2.x, ay = R2.y, a1 = R2.z, fgadd = R2.w;
        const float p0 = R3.x, p1 = R3.y, p2 = R3.z, p3 = R3.w;
        const float p4 = R4.x, p5 = R4.y;
        const float cc = CB[r * CN + lab];

        // iou / giou (f32, reference op order)
        float ltx = fmaxf(b0, g0), lty = fmaxf(b1, g1);
        float rbx = fminf(b2, g2), rby = fminf(b3, g3);
        float w = fmaxf(rbx - ltx, 0.0f), h = fmaxf(rby - lty, 0.0f);
        float inter = w * h;
        float uni = (a1 + ga) - inter;
        float iou = inter / uni;
        float eltx = fminf(b0, g0), elty = fminf(b1, g1);
        float erbx = fmaxf(b2, g2), erby = fmaxf(b3, g3);
        float ew = fmaxf(erbx - eltx, 0.0f), eh = fmaxf(erby - elty, 0.0f);
        float earea = ew * eh;
        float giou = iou - (earea - uni) / earea;

        // normalized bbox L1 (sequential f32)
        float cb = fabsf(bn0 - gn0);
        cb = cb + fabsf(bn1 - gn1);
        cb = cb + fabsf(bn2 - gn2);
        cb = cb + fabsf(bn3 - gn3);
        // pose L1
        float ct = fabsf(p0 - t0); ct = ct + fabsf(p1 - t1); ct = ct + fabsf(p2 - t2);
        float cr = fabsf(p3 - r0); cr = cr + fabsf(p4 - r1); cr = cr + fabsf(p5 - r2);
        // both
        bool ib = (ax > X0) && (ax < X1) && (ay > Y0) && (ay < Y1);
        bool ic = (ax > LOX) && (ax < HIX) && (ay > LOY) && (ay < HIY);
        bool nb = !(ib && ic);

        float d = 5.0f * cb;
        d = d + 2.0f * cc;
        d = d + 2.0f * (-giou);
        d = d + (nb ? 100.0f : 0.0f);
        d = d + ct;
        d = d + cr;
        d = d + fgadd;

        CT[(size_t)r * GN] = d;

        // bottom-5 via u64 key cascade (order-isomorphic to (cost,i) lex)
        u64 key = ((u64)fkey(d) << 32) | (unsigned int)i;
        if (key < ck[4]) {
#pragma unroll
            for (int k = 0; k < 5; k++) {
                u64 mn = key < ck[k] ? key : ck[k];
                u64 mx = key < ck[k] ? ck[k] : key;
                ck[k] = mn; key = mx;
            }
        }
        // top-5 iou via max/min network (tie values identical -> bitwise same)
        if (iou > iv[4]) {
            float fv = iou;
#pragma unroll
            for (int k = 0; k < 5; k++) {
                float mx = fmaxf(fv, iv[k]);
                fv = fminf(fv, iv[k]);
                iv[k] = mx;
            }
        }
    }

    const int col = b * GN + j;
    const size_t base = ((size_t)part * (BN * GN) + col) * 5;
#pragma unroll
    for (int k = 0; k < 5; k++) { pck[base + k] = ck[k]; piv[base + k] = iv[k]; }
}

// ---------------- merge parts (wave butterfly), dk, rowmask, amin init ----------------
__global__ __launch_bounds__(256) void k_dk(const u64* __restrict__ pck,
                                            const float* __restrict__ piv,
                                            float* __restrict__ candcv, int* __restrict__ candci,
                                            int* __restrict__ dkArr, u64* __restrict__ rowmask,
                                            u64* __restrict__ amin) {
#pragma clang fp contract(off)
    const int lane = threadIdx.x & 63;
    const int colIdx = blockIdx.x * 4 + (threadIdx.x >> 6);   // 4 waves/block
    const int b = colIdx >> 8, j = colIdx & 255;
    const size_t base0 = ((size_t)lane * (BN * GN) + colIdx) * 5;
    const size_t base1 = ((size_t)(lane + 64) * (BN * GN) + colIdx) * 5;
    u64 rv[5]; float fr[5];
#pragma unroll
    for (int k = 0; k < 5; k++) { rv[k] = pck[base0 + k]; fr[k] = piv[base0 + k]; }
    // pre-merge second part
#pragma unroll
    for (int m = 0; m < 5; m++) {
        u64 key = pck[base1 + m];
        if (key < rv[4]) {
#pragma unroll
            for (int k = 0; k < 5; k++) {
                u64 mn = key < rv[k] ? key : rv[k];
                u64 mx = key < rv[k] ? rv[k] : key;
                rv[k] = mn; key = mx;
            }
        }
        float fv = piv[base1 + m];
        if (fv > fr[4]) {
#pragma unroll
            for (int k = 0; k < 5; k++) {
                float mx = fmaxf(fv, fr[k]);
                fv = fminf(fv, fr[k]);
                fr[k] = mx;
            }
        }
    }
    // butterfly over 64 lanes
    for (int off = 1; off < 64; off <<= 1) {
        u64 ov[5]; float of[5];
#pragma unroll
        for (int m = 0; m < 5; m++) {
            ov[m] = __shfl_xor(rv[m], off, 64);
            of[m] = __shfl_xor(fr[m], off, 64);
        }
#pragma unroll
        for (int m = 0; m < 5; m++) {
            u64 key = ov[m];
            if (key < rv[4]) {
#pragma unroll
                for (int k = 0; k < 5; k++) {
                    u64 mn = key < rv[k] ? key : rv[k];
                    u64 mx = key < rv[k] ? rv[k] : key;
                    rv[k] = mn; key = mx;
                }
            }
            float fv = of[m];
            if (fv > fr[4]) {
#pragma unroll
                for (int k = 0; k < 5; k++) {
                    float mx = fmaxf(fv, fr[k]);
                    fv = fminf(fv, fr[k]);
                    fr[k] = mx;
                }
            }
        }
    }

    if (lane == 0) {
        float sum = ((((fr[0] + fr[1]) + fr[2]) + fr[3]) + fr[4]);  // desc order, sequential
        int dk = (int)sum;
        if (dk < 1) dk = 1;
        if (dk > 5) dk = 5;
        dkArr[colIdx] = dk;
        amin[colIdx] = ~0ull;
#pragma unroll
        for (int k = 0; k < 5; k++) {
            candcv[(size_t)colIdx * 5 + k] = funkey((unsigned int)(rv[k] >> 32));
            candci[(size_t)colIdx * 5 + k] = (int)(unsigned int)(rv[k] & 0xFFFFFFFFull);
        }
        for (int k = 0; k < dk; k++) {
            int i = (int)(unsigned int)(rv[k] & 0xFFFFFFFFull);
            atomicOr(&rowmask[((size_t)(b * QN + i)) * 4 + (j >> 6)], 1ull << (j & 63));
        }
    }
}

// ---------------- stale detect + pen + colcnt ----------------
__global__ __launch_bounds__(256) void k_stalepen(u64* __restrict__ rowmask,
                                                  unsigned char* __restrict__ pen,
                                                  int* __restrict__ colcnt,
                                                  int* __restrict__ staleCount,
                                                  int* __restrict__ staleList) {
    int b = blockIdx.y;
    int i = blockIdx.x * 256 + threadIdx.x;
    u64* rm = rowmask + ((size_t)(b * QN + i)) * 4;
    u64 w0 = rm[0], w1 = rm[1], w2 = rm[2], w3 = rm[3];
    int cnt = __popcll(w0) + __popcll(w1) + __popcll(w2) + __popcll(w3);
    pen[(size_t)b * QN + i] = (cnt > 0) ? 1 : 0;
    if (cnt > 1) {
        int idx = atomicAdd(staleCount, 1);
        staleList[idx] = (b << 12) | i;
    } else if (cnt == 1) {
        u64 w; int base;
        if (w0) { w = w0; base = 0; }
        else if (w1) { w = w1; base = 64; }
        else if (w2) { w = w2; base = 128; }
        else { w = w3; base = 192; }
        int j = base + (__ffsll((long long)w) - 1);
        atomicAdd(&colcnt[b * GN + j], 1);
    }
}

// ---------------- stale fix: row -> one_hot(argmin_j costT[row][:]) ----------------
__global__ __launch_bounds__(256) void k_stalefix(const float* __restrict__ costT,
                                                  u64* __restrict__ rowmask,
                                                  int* __restrict__ colcnt,
                                                  const int* __restrict__ staleCount,
                                                  const int* __restrict__ staleList,
                                                  int* __restrict__ fixBj) {
    int gtid = blockIdx.x * blockDim.x + threadIdx.x;
    int wid = gtid >> 6;
    int lane = threadIdx.x & 63;
    int nw = (gridDim.x * blockDim.x) >> 6;
    int n = *staleCount;
    for (int e = wid; e < n; e += nw) {
        int pk = staleList[e];
        int b = pk >> 12, i = pk & 4095;
        const float* cb = costT + ((size_t)(b * QN) + i) * GN;   // contiguous row
        float best = FLT_MAX; int bj = GN;
        for (int k = 0; k < GN; k += 64) {
            int j = k + lane;
            float v = cb[j];
            if (lexLessF(v, j, best, bj)) { best = v; bj = j; }
        }
        for (int off = 32; off > 0; off >>= 1) {
            float ov = __shfl_down(best, off, 64);
            int oj = __shfl_down(bj, off, 64);
            if (lexLessF(ov, oj, best, bj)) { best = ov; bj = oj; }
        }
        if (lane == 0) {
            u64* rm = rowmask + ((size_t)(b * QN + i)) * 4;
            rm[0] = ((bj >> 6) == 0) ? (1ull << (bj & 63)) : 0ull;
            rm[1] = ((bj >> 6) == 1) ? (1ull << (bj & 63)) : 0ull;
            rm[2] = ((bj >> 6) == 2) ? (1ull << (bj & 63)) : 0ull;
            rm[3] = ((bj >> 6) == 3) ? (1ull << (bj & 63)) : 0ull;
            atomicAdd(&colcnt[b * GN + bj], 1);
            fixBj[e] = bj;
        }
    }
}

// ---------------- assign: coalesced row scan + atomicMin on u64 key ----------------
__global__ __launch_bounds__(256) void k_assign(const float* __restrict__ costT,
                                                const unsigned char* __restrict__ pen,
                                                const int* __restrict__ colcnt,
                                                u64* __restrict__ amin) {
    const int j = threadIdx.x;
    const int b = blockIdx.y;
    const int i0 = blockIdx.x * 256;
    u64 best = ~0ull;
    const unsigned char* pp = pen + (size_t)b * QN + i0;
    const float* C = costT + ((size_t)(b * QN) + i0) * GN + j;
    for (int r = 0; r < 256; r++) {
        if (!pp[r]) {                                   // wave-uniform branch
            float v = C[(size_t)r * GN];
            u64 key = ((u64)fkey(v) << 32) | (unsigned int)(i0 + r);
            best = key < best ? key : best;
        }
    }
    if (colcnt[b * GN + j] == 0 && best != ~0ull)
        atomicMin(&amin[b * GN + j], best);
}

__global__ void k_assignfix(const u64* __restrict__ amin,
                            const int* __restrict__ colcnt,
                            int* __restrict__ assign, u64* __restrict__ rowmask) {
    const int col = blockIdx.x * 256 + threadIdx.x;
    const int b = col >> 8, j = col & 255;
    if (colcnt[col] != 0) { assign[col] = -1; return; }
    u64 key = amin[col];
    int r = (int)(unsigned int)(key & 0xFFFFFFFFull);
    assign[col] = r;
    atomicOr(&rowmask[((size_t)(b * QN + r)) * 4 + (j >> 6)], 1ull << (j & 63));
}

// ---------------- per-row outputs: selected, gt_idx ----------------
__global__ __launch_bounds__(256) void k_outrows(const u64* __restrict__ rowmask,
                                                 int* __restrict__ out) {
    int b = blockIdx.y;
    int i = blockIdx.x * 256 + threadIdx.x;
    const u64* rm = rowmask + ((size_t)(b * QN + i)) * 4;
    u64 w0 = rm[0], w1 = rm[1], w2 = rm[2], w3 = rm[3];
    int sel = (w0 | w1 | w2 | w3) ? 1 : 0;
    int g = 0;
    if (w0) g = __ffsll((long long)w0) - 1;
    else if (w1) g = 64 + __ffsll((long long)w1) - 1;
    else if (w2) g = 128 + __ffsll((long long)w2) - 1;
    else if (w3) g = 192 + __ffsll((long long)w3) - 1;
    out[(size_t)b * QN + i] = sel;
    out[(size_t)BN * QN + (size_t)b * QN + i] = g;
}

// ---------------- per-column output: matched_qidx (candidate-based) ----------------
__global__ __launch_bounds__(256) void k_outcols(const float* __restrict__ costT,
                                                 const u64* __restrict__ rowmask,
                                                 const int* __restrict__ assign,
                                                 const float* __restrict__ candcv,
                                                 const int* __restrict__ candci,
                                                 const int* __restrict__ dkArr,
                                                 const int* __restrict__ staleCount,
                                                 const int* __restrict__ staleList,
                                                 const int* __restrict__ fixBj,
                                                 int* __restrict__ out) {
    const int b = blockIdx.x;
    const int j = threadIdx.x;
    const int col = b * GN + j;
    int* o = out + (size_t)2 * BN * QN + col;
    int a = assign[col];
    if (a >= 0) { *o = a; return; }
    const u64 bit = 1ull << (j & 63);
    const int w = j >> 6;
    float best = FLT_MAX; int bi = INT_MAX;
    const int dk = dkArr[col];
    for (int k = 0; k < 5; k++) {
        if (k < dk) {
            int i = candci[(size_t)col * 5 + k];
            if (rowmask[((size_t)(b * QN + i)) * 4 + w] & bit) {
                float pv = candcv[(size_t)col * 5 + k] + 100000.0f;
                if (lexLessF(pv, i, best, bi)) { best = pv; bi = i; }
            }
        }
    }
    const int n = *staleCount;
    for (int e = 0; e < n; e++) {
        int pk = staleList[e];
        int eb = pk >> 12, ei = pk & 4095;
        if (eb == b && fixBj[e] == j) {
            float pv = costT[((size_t)(b * QN) + ei) * GN + j] + 100000.0f;
            if (lexLessF(pv, ei, best, bi)) { best = pv; bi = ei; }
        }
    }
    *o = (bi == INT_MAX) ? 0 : bi;
}

extern "C" void kernel_launch(void* const* d_in, const int* in_sizes, int n_in,
                              void* d_out, int out_size, void* d_ws, size_t ws_size,
                              hipStream_t stream) {
    const float* logits = (const float*)d_in[0];
    const float* pboxes = (const float*)d_in[1];
    const float* pposes = (const float*)d_in[2];
    const int* labels = (const int*)d_in[3];
    const float* gtb = (const float*)d_in[4];
    const float* gtt = (const float*)d_in[5];
    const float* gtr = (const float*)d_in[6];
    const float* img = (const float*)d_in[7];
    const float* imgt = (const float*)d_in[8];
    int* out = (int*)d_out;

    char* p = (char*)d_ws;
    float* costT = (float*)p;            p += (size_t)BN * QN * GN * 4;        // 64 MiB
    float* cclsT = (float*)p;            p += (size_t)BN * QN * CN * 4;        // 20 MiB
    float* rowp = (float*)p;             p += (size_t)BN * QN * 20 * 4;        // 5 MiB
    u64* pck = (u64*)p;                  p += (size_t)NPART * BN * GN * 5 * 8; // 20 MiB
    float* piv = (float*)p;              p += (size_t)NPART * BN * GN * 5 * 4; // 10 MiB
    u64* rowmask = (u64*)p;              size_t rb = (size_t)BN * QN * 4 * 8; p += rb;  // 2 MiB
    int* colcnt = (int*)p;               p += (size_t)BN * GN * 4;             // 16 KiB
    int* staleCount = (int*)p;           p += 64;
    int* staleList = (int*)p;            p += (size_t)BN * QN * 4;             // 256 KiB
    int* fixBj = (int*)p;                p += (size_t)BN * QN * 4;             // 256 KiB
    unsigned char* pen = (unsigned char*)p; p += (size_t)BN * QN;              // 64 KiB
    unsigned char* fgp = (unsigned char*)p; p += (size_t)BN * QN * 4;          // 256 KiB
    int* assign = (int*)p;               p += (size_t)BN * GN * 4;             // 16 KiB
    float* prmT = (float*)p;             p += (size_t)BN * NPRM * GN * 4;      // 376 KiB
    float* candcv = (float*)p;           p += (size_t)BN * GN * 5 * 4;         // 80 KiB
    int* candci = (int*)p;               p += (size_t)BN * GN * 5 * 4;         // 80 KiB
    int* dkArr = (int*)p;                p += (size_t)BN * GN * 4;             // 16 KiB
    u64* amin = (u64*)p;                 p += (size_t)BN * GN * 8;             // 32 KiB

    // zero rowmask + colcnt + staleCount (contiguous)
    int zn = (int)((rb + (size_t)BN * GN * 4 + 64) / 8);
    k_zero<<<(zn + 255) / 256, 256, 0, stream>>>(rowmask, zn);

    k_class<<<BN * 64, 256, 0, stream>>>(logits, gtb, gtt, gtr, imgt, cclsT, prmT);
    k_fg<<<dim3(QN / 256, BN, 4), 256, 0, stream>>>(gtb, pboxes, fgp);
    k_rows<<<dim3(QN / 256, BN), 256, 0, stream>>>(pboxes, pposes, img,
                                                   (const unsigned int*)fgp, rowp);
    k_main<<<BN * NPART, 256, 0, stream>>>(cclsT, labels, prmT, rowp, costT, pck, piv);
    k_dk<<<BN * GN / 4, 256, 0, stream>>>(pck, piv, candcv, candci, dkArr, rowmask, amin);
    k_stalepen<<<dim3(QN / 256, BN), 256, 0, stream>>>(rowmask, pen, colcnt, staleCount, staleList);
    k_stalefix<<<256, 256, 0, stream>>>(costT, rowmask, colcnt, staleCount, staleList, fixBj);
    k_assign<<<dim3(QN / 256, BN), 256, 0, stream>>>(costT, pen, colcnt, amin);
    k_assignfix<<<BN * GN / 256, 256, 0, stream>>>(amin, colcnt, assign, rowmask);
    k_outrows<<<dim3(QN / 256, BN), 256, 0, stream>>>(rowmask, out);
    k_outcols<<<BN, 256, 0, stream>>>(costT, rowmask, assign, candcv, candci, dkArr,
                                      staleCount, staleList, fixBj, out);
}

// Round 13
// 327.645 us; speedup vs baseline: 1.2722x; 1.2722x over previous
//
#include <hip/hip_runtime.h>
#include <cfloat>
#include <climits>
#include <math.h>

#define BN 16
#define QN 4096
#define GN 256
#define CN 80
#define NPART 128          // row parts in k_main (32 rows each)
#define RPP (QN / NPART)   // 32
#define NPRM 23            // column params

typedef unsigned long long u64;

__device__ __forceinline__ bool lexLessF(float a, int ia, float b, int ib) {
    return (a < b) || (a == b && ia < ib);
}
// IEEE order-isomorphic u32 key (no NaNs in this data)
__device__ __forceinline__ unsigned int fkey(float f) {
    unsigned int b = __float_as_uint(f);
    return b ^ ((b >> 31) ? 0xFFFFFFFFu : 0x80000000u);
}
__device__ __forceinline__ float funkey(unsigned int k) {
    unsigned int b = k ^ ((k >> 31) ? 0x80000000u : 0xFFFFFFFFu);
    return __uint_as_float(b);
}

// ---------------- zero init (rowmask + colcnt + staleCount) ----------------
__global__ void k_zero(u64* __restrict__ p, int n) {
    int i = blockIdx.x * blockDim.x + threadIdx.x;
    if (i < n) p[i] = 0ull;
}

// ---------------- focal class-cost table (TRANSPOSED [b][i][c]) + prmT ----------------
__global__ __launch_bounds__(256) void k_class(const float* __restrict__ logits,
                                               const float* __restrict__ gtb,
                                               const float* __restrict__ gtt,
                                               const float* __restrict__ gtr,
                                               const float* __restrict__ imgt,
                                               float* __restrict__ cclsT,
                                               float* __restrict__ prmT) {
#pragma clang fp contract(off)
    const int b = blockIdx.x >> 6, iblk = blockIdx.x & 63;
    const int lane = threadIdx.x & 63, cg = threadIdx.x >> 6;  // 4 c-groups x 20
    const int i = iblk * 64 + lane;
    const float* lrow = logits + ((size_t)(b * QN + i)) * CN + cg * 20;
    float* orow = cclsT + ((size_t)(b * QN + i)) * CN + cg * 20;
#pragma unroll
    for (int q = 0; q < 5; q++) {
        const float4 xv = *reinterpret_cast<const float4*>(lrow + q * 4);
        float xs[4] = {xv.x, xv.y, xv.z, xv.w};
        float os[4];
#pragma unroll
        for (int u = 0; u < 4; u++) {
            float x = xs[u];
            float e = (float)exp(-(double)x);
            float pr = 1.0f / (1.0f + e);
            float om = 1.0f - pr;
            float lneg = (float)log((double)(om + 1e-8f));
            float lpos = (float)log((double)(pr + 1e-8f));
            float neg = (0.75f * (pr * pr)) * (-lneg);
            float pos = (0.25f * (om * om)) * (-lpos);
            os[u] = pos - neg;
        }
        *reinterpret_cast<float4*>(orow + q * 4) = make_float4(os[0], os[1], os[2], os[3]);
    }
    if (iblk == 0) {
        const int j = threadIdx.x;
        const float* g = gtb + ((size_t)(b * GN + j)) * 4;
        const float g0 = g[0], g1 = g[1], g2 = g[2], g3 = g[3];
        const float* it = imgt + ((size_t)(b * GN + j)) * 4;
        float* P = prmT + (size_t)b * NPRM * GN;
        P[0 * GN + j] = g0; P[1 * GN + j] = g1; P[2 * GN + j] = g2; P[3 * GN + j] = g3;
        P[4 * GN + j] = g0 / it[0]; P[5 * GN + j] = g1 / it[1];
        P[6 * GN + j] = g2 / it[2]; P[7 * GN + j] = g3 / it[3];
        P[8 * GN + j] = gtt[(b * GN + j) * 3 + 0]; P[9 * GN + j] = gtt[(b * GN + j) * 3 + 1];
        P[10 * GN + j] = gtt[(b * GN + j) * 3 + 2];
        P[11 * GN + j] = gtr[(b * GN + j) * 3 + 0]; P[12 * GN + j] = gtr[(b * GN + j) * 3 + 1];
        P[13 * GN + j] = gtr[(b * GN + j) * 3 + 2];
        P[14 * GN + j] = (g2 - g0) * (g3 - g1);   // ga
        float gcx = (g0 + g2) * 0.5f, gcy = (g1 + g3) * 0.5f;
        float gw = g2 - g0, gh = g3 - g1;
        float X0 = gcx - gw * 0.5f, Y0 = gcy - gh * 0.5f;
        float X1 = gcx + gw * 0.5f, Y1 = gcy + gh * 0.5f;
        float Wd = X1 - X0, Hd = Y1 - Y0;
        P[15 * GN + j] = X0; P[16 * GN + j] = Y0; P[17 * GN + j] = X1; P[18 * GN + j] = Y1;
        P[19 * GN + j] = gcx - 2.5f * Wd; P[20 * GN + j] = gcx + 2.5f * Wd;
        P[21 * GN + j] = gcy - 2.5f * Hd; P[22 * GN + j] = gcy + 2.5f * Hd;
    }
}

// ---------------- fg per query row, 4-way j-split ----------------
__global__ __launch_bounds__(256) void k_fg(const float* __restrict__ gtb,
                                            const float* __restrict__ pb,
                                            unsigned char* __restrict__ fgp) {
#pragma clang fp contract(off)
    const int b = blockIdx.y;
    const int part = blockIdx.z;
    const int i = blockIdx.x * 256 + threadIdx.x;
    __shared__ float s[64][8];
    if (threadIdx.x < 64) {
        const int j = part * 64 + threadIdx.x;
        const float* g = gtb + ((size_t)(b * GN + j)) * 4;
        float g0 = g[0], g1 = g[1], g2 = g[2], g3 = g[3];
        float gcx = (g0 + g2) * 0.5f, gcy = (g1 + g3) * 0.5f;
        float gw = g2 - g0, gh = g3 - g1;
        float x0 = gcx - gw * 0.5f, y0 = gcy - gh * 0.5f;
        float x1 = gcx + gw * 0.5f, y1 = gcy + gh * 0.5f;
        float w = x1 - x0, h = y1 - y0;
        s[threadIdx.x][0] = x0; s[threadIdx.x][1] = y0; s[threadIdx.x][2] = x1; s[threadIdx.x][3] = y1;
        s[threadIdx.x][4] = gcx - 2.5f * w; s[threadIdx.x][5] = gcx + 2.5f * w;
        s[threadIdx.x][6] = gcy - 2.5f * h; s[threadIdx.x][7] = gcy + 2.5f * h;
    }
    __syncthreads();
    const float4 bb = *reinterpret_cast<const float4*>(pb + ((size_t)(b * QN + i)) * 4);
    float ax = (bb.x + bb.z) * 0.5f, ay = (bb.y + bb.w) * 0.5f;
    bool anyib = false, anyic = false;
#pragma unroll 8
    for (int j = 0; j < 64; j++) {
        bool ib = (ax > s[j][0]) && (ax < s[j][2]) && (ay > s[j][1]) && (ay < s[j][3]);
        bool ic = (ax > s[j][4]) && (ax < s[j][5]) && (ay > s[j][6]) && (ay < s[j][7]);
        anyib |= ib; anyic |= ic;
    }
    fgp[((size_t)b * QN + i) * 4 + part] = (anyib || anyic) ? 1 : 0;
}

// ---------------- per-row common table rowp[b][i][20] ----------------
__global__ __launch_bounds__(256) void k_rows(const float* __restrict__ pboxes,
                                              const float* __restrict__ pposes,
                                              const float* __restrict__ img,
                                              const unsigned int* __restrict__ fgw,
                                              float* __restrict__ rowp) {
#pragma clang fp contract(off)
    const int b = blockIdx.y;
    const int i = blockIdx.x * 256 + threadIdx.x;
    const float im0 = img[b * 4 + 0], im1 = img[b * 4 + 1], im2 = img[b * 4 + 2], im3 = img[b * 4 + 3];
    const float4 bx = *reinterpret_cast<const float4*>(pboxes + ((size_t)(b * QN + i)) * 4);
    const float b0 = bx.x, b1 = bx.y, b2 = bx.z, b3 = bx.w;
    const float2* pp2 = reinterpret_cast<const float2*>(pposes + ((size_t)(b * QN + i)) * 6);
    const float2 q0 = pp2[0], q1 = pp2[1], q2 = pp2[2];
    const float fgadd = fgw[(size_t)b * QN + i] ? 0.0f : 10000.0f;
    const float bn0 = b0 / im0, bn1 = b1 / im1, bn2 = b2 / im2, bn3 = b3 / im3;
    const float a1 = (b2 - b0) * (b3 - b1);
    const float ax = (b0 + b2) * 0.5f, ay = (b1 + b3) * 0.5f;
    float4* R = reinterpret_cast<float4*>(rowp + ((size_t)(b * QN) + i) * 20);
    R[0] = make_float4(b0, b1, b2, b3);
    R[1] = make_float4(bn0, bn1, bn2, bn3);
    R[2] = make_float4(ax, ay, a1, fgadd);
    R[3] = make_float4(q0.x, q0.y, q1.x, q1.y);
    R[4] = make_float4(q2.x, q2.y, 0.0f, 0.0f);
}

// ---------------- fused cost + selection: column-per-thread, u64 keys ----------------
__global__ __launch_bounds__(256) void k_main(
    const float* __restrict__ cclsT, const int* __restrict__ labels,
    const float* __restrict__ prmT, const float* __restrict__ rowp,
    float* __restrict__ costT,
    u64* __restrict__ pck, float* __restrict__ piv) {
#pragma clang fp contract(off)
    const int j = threadIdx.x;
    const int b = blockIdx.x >> 7;
    const int part = blockIdx.x & 127;
    const int i0 = part * RPP;
    const float* P = prmT + (size_t)b * NPRM * GN;
    const float g0 = P[0 * GN + j], g1 = P[1 * GN + j], g2 = P[2 * GN + j], g3 = P[3 * GN + j];
    const float gn0 = P[4 * GN + j], gn1 = P[5 * GN + j], gn2 = P[6 * GN + j], gn3 = P[7 * GN + j];
    const float t0 = P[8 * GN + j], t1 = P[9 * GN + j], t2 = P[10 * GN + j];
    const float r0 = P[11 * GN + j], r1 = P[12 * GN + j], r2 = P[13 * GN + j];
    const float ga = P[14 * GN + j];
    const float X0 = P[15 * GN + j], Y0 = P[16 * GN + j], X1 = P[17 * GN + j], Y1 = P[18 * GN + j];
    const float LOX = P[19 * GN + j], HIX = P[20 * GN + j], LOY = P[21 * GN + j], HIY = P[22 * GN + j];
    const int lab = labels[b * GN + j];

    const float* RB = rowp + ((size_t)(b * QN) + i0) * 20;      // uniform base
    const float* CB = cclsT + ((size_t)(b * QN) + i0) * CN;     // uniform base + lab
    float* CT = costT + ((size_t)(b * QN) + i0) * GN + j;

    u64 ck[5]; float iv[5];
#pragma unroll
    for (int k = 0; k < 5; k++) { ck[k] = ~0ull; iv[k] = -1.0f; }

    for (int r = 0; r < RPP; r++) {
        const int i = i0 + r;
        const float4 R0 = *reinterpret_cast<const float4*>(RB + r * 20 + 0);   // uniform -> s_load
        const float4 R1 = *reinterpret_cast<const float4*>(RB + r * 20 + 4);
        const float4 R2 = *reinterpret_cast<const float4*>(RB + r * 20 + 8);
        const float4 R3 = *reinterpret_cast<const float4*>(RB + r * 20 + 12);
        const float4 R4 = *reinterpret_cast<const float4*>(RB + r * 20 + 16);
        const float b0 = R0.x, b1 = R0.y, b2 = R0.z, b3 = R0.w;
        const float bn0 = R1.x, bn1 = R1.y, bn2 = R1.z, bn3 = R1.w;
        const float ax = R2.x, ay = R2.y, a1 = R2.z, fgadd = R2.w;
        const float p0 = R3.x, p1 = R3.y, p2 = R3.z, p3 = R3.w;
        const float p4 = R4.x, p5 = R4.y;
        const float cc = CB[r * CN + lab];

        // iou / giou (f32, reference op order)
        float ltx = fmaxf(b0, g0), lty = fmaxf(b1, g1);
        float rbx = fminf(b2, g2), rby = fminf(b3, g3);
        float w = fmaxf(rbx - ltx, 0.0f), h = fmaxf(rby - lty, 0.0f);
        float inter = w * h;
        float uni = (a1 + ga) - inter;
        float iou = inter / uni;
        float eltx = fminf(b0, g0), elty = fminf(b1, g1);
        float erbx = fmaxf(b2, g2), erby = fmaxf(b3, g3);
        float ew = fmaxf(erbx - eltx, 0.0f), eh = fmaxf(erby - elty, 0.0f);
        float earea = ew * eh;
        float giou = iou - (earea - uni) / earea;

        // normalized bbox L1 (sequential f32)
        float cb = fabsf(bn0 - gn0);
        cb = cb + fabsf(bn1 - gn1);
        cb = cb + fabsf(bn2 - gn2);
        cb = cb + fabsf(bn3 - gn3);
        // pose L1
        float ct = fabsf(p0 - t0); ct = ct + fabsf(p1 - t1); ct = ct + fabsf(p2 - t2);
        float cr = fabsf(p3 - r0); cr = cr + fabsf(p4 - r1); cr = cr + fabsf(p5 - r2);
        // both
        bool ib = (ax > X0) && (ax < X1) && (ay > Y0) && (ay < Y1);
        bool ic = (ax > LOX) && (ax < HIX) && (ay > LOY) && (ay < HIY);
        bool nb = !(ib && ic);

        float d = 5.0f * cb;
        d = d + 2.0f * cc;
        d = d + 2.0f * (-giou);
        d = d + (nb ? 100.0f : 0.0f);
        d = d + ct;
        d = d + cr;
        d = d + fgadd;

        CT[(size_t)r * GN] = d;

        // bottom-5 via u64 key cascade (order-isomorphic to (cost,i) lex)
        u64 key = ((u64)fkey(d) << 32) | (unsigned int)i;
        if (key < ck[4]) {
#pragma unroll
            for (int k = 0; k < 5; k++) {
                u64 mn = key < ck[k] ? key : ck[k];
                u64 mx = key < ck[k] ? ck[k] : key;
                ck[k] = mn; key = mx;
            }
        }
        // top-5 iou via max/min network (tie values identical -> bitwise same)
        if (iou > iv[4]) {
            float fv = iou;
#pragma unroll
            for (int k = 0; k < 5; k++) {
                float mx = fmaxf(fv, iv[k]);
                fv = fminf(fv, iv[k]);
                iv[k] = mx;
            }
        }
    }

    const int col = b * GN + j;
    const size_t base = ((size_t)part * (BN * GN) + col) * 5;
#pragma unroll
    for (int k = 0; k < 5; k++) { pck[base + k] = ck[k]; piv[base + k] = iv[k]; }
}

// ---------------- merge parts (wave butterfly), dk, rowmask, amin init ----------------
__global__ __launch_bounds__(256) void k_dk(const u64* __restrict__ pck,
                                            const float* __restrict__ piv,
                                            float* __restrict__ candcv, int* __restrict__ candci,
                                            int* __restrict__ dkArr, u64* __restrict__ rowmask,
                                            u64* __restrict__ amin) {
#pragma clang fp contract(off)
    const int lane = threadIdx.x & 63;
    const int colIdx = blockIdx.x * 4 + (threadIdx.x >> 6);   // 4 waves/block
    const int b = colIdx >> 8, j = colIdx & 255;
    const size_t base0 = ((size_t)lane * (BN * GN) + colIdx) * 5;
    const size_t base1 = ((size_t)(lane + 64) * (BN * GN) + colIdx) * 5;
    u64 rv[5]; float fr[5];
#pragma unroll
    for (int k = 0; k < 5; k++) { rv[k] = pck[base0 + k]; fr[k] = piv[base0 + k]; }
    // pre-merge second part
#pragma unroll
    for (int m = 0; m < 5; m++) {
        u64 key = pck[base1 + m];
        if (key < rv[4]) {
#pragma unroll
            for (int k = 0; k < 5; k++) {
                u64 mn = key < rv[k] ? key : rv[k];
                u64 mx = key < rv[k] ? rv[k] : key;
                rv[k] = mn; key = mx;
            }
        }
        float fv = piv[base1 + m];
        if (fv > fr[4]) {
#pragma unroll
            for (int k = 0; k < 5; k++) {
                float mx = fmaxf(fv, fr[k]);
                fv = fminf(fv, fr[k]);
                fr[k] = mx;
            }
        }
    }
    // butterfly over 64 lanes
    for (int off = 1; off < 64; off <<= 1) {
        u64 ov[5]; float of[5];
#pragma unroll
        for (int m = 0; m < 5; m++) {
            ov[m] = __shfl_xor(rv[m], off, 64);
            of[m] = __shfl_xor(fr[m], off, 64);
        }
#pragma unroll
        for (int m = 0; m < 5; m++) {
            u64 key = ov[m];
            if (key < rv[4]) {
#pragma unroll
                for (int k = 0; k < 5; k++) {
                    u64 mn = key < rv[k] ? key : rv[k];
                    u64 mx = key < rv[k] ? rv[k] : key;
                    rv[k] = mn; key = mx;
                }
            }
            float fv = of[m];
            if (fv > fr[4]) {
#pragma unroll
                for (int k = 0; k < 5; k++) {
                    float mx = fmaxf(fv, fr[k]);
                    fv = fminf(fv, fr[k]);
                    fr[k] = mx;
                }
            }
        }
    }

    if (lane == 0) {
        float sum = ((((fr[0] + fr[1]) + fr[2]) + fr[3]) + fr[4]);  // desc order, sequential
        int dk = (int)sum;
        if (dk < 1) dk = 1;
        if (dk > 5) dk = 5;
        dkArr[colIdx] = dk;
        amin[colIdx] = ~0ull;
#pragma unroll
        for (int k = 0; k < 5; k++) {
            candcv[(size_t)colIdx * 5 + k] = funkey((unsigned int)(rv[k] >> 32));
            candci[(size_t)colIdx * 5 + k] = (int)(unsigned int)(rv[k] & 0xFFFFFFFFull);
        }
        for (int k = 0; k < dk; k++) {
            int i = (int)(unsigned int)(rv[k] & 0xFFFFFFFFull);
            atomicOr(&rowmask[((size_t)(b * QN + i)) * 4 + (j >> 6)], 1ull << (j & 63));
        }
    }
}

// ---------------- stale detect + pen + colcnt ----------------
__global__ __launch_bounds__(256) void k_stalepen(u64* __restrict__ rowmask,
                                                  unsigned char* __restrict__ pen,
                                                  int* __restrict__ colcnt,
                                                  int* __restrict__ staleCount,
                                                  int* __restrict__ staleList) {
    int b = blockIdx.y;
    int i = blockIdx.x * 256 + threadIdx.x;
    u64* rm = rowmask + ((size_t)(b * QN + i)) * 4;
    u64 w0 = rm[0], w1 = rm[1], w2 = rm[2], w3 = rm[3];
    int cnt = __popcll(w0) + __popcll(w1) + __popcll(w2) + __popcll(w3);
    pen[(size_t)b * QN + i] = (cnt > 0) ? 1 : 0;
    if (cnt > 1) {
        int idx = atomicAdd(staleCount, 1);
        staleList[idx] = (b << 12) | i;
    } else if (cnt == 1) {
        u64 w; int base;
        if (w0) { w = w0; base = 0; }
        else if (w1) { w = w1; base = 64; }
        else if (w2) { w = w2; base = 128; }
        else { w = w3; base = 192; }
        int j = base + (__ffsll((long long)w) - 1);
        atomicAdd(&colcnt[b * GN + j], 1);
    }
}

// ---------------- stale fix: row -> one_hot(argmin_j costT[row][:]) ----------------
__global__ __launch_bounds__(256) void k_stalefix(const float* __restrict__ costT,
                                                  u64* __restrict__ rowmask,
                                                  int* __restrict__ colcnt,
                                                  const int* __restrict__ staleCount,
                                                  const int* __restrict__ staleList,
                                                  int* __restrict__ fixBj) {
    int gtid = blockIdx.x * blockDim.x + threadIdx.x;
    int wid = gtid >> 6;
    int lane = threadIdx.x & 63;
    int nw = (gridDim.x * blockDim.x) >> 6;
    int n = *staleCount;
    for (int e = wid; e < n; e += nw) {
        int pk = staleList[e];
        int b = pk >> 12, i = pk & 4095;
        const float* cb = costT + ((size_t)(b * QN) + i) * GN;   // contiguous row
        float best = FLT_MAX; int bj = GN;
        for (int k = 0; k < GN; k += 64) {
            int j = k + lane;
            float v = cb[j];
            if (lexLessF(v, j, best, bj)) { best = v; bj = j; }
        }
        for (int off = 32; off > 0; off >>= 1) {
            float ov = __shfl_down(best, off, 64);
            int oj = __shfl_down(bj, off, 64);
            if (lexLessF(ov, oj, best, bj)) { best = ov; bj = oj; }
        }
        if (lane == 0) {
            u64* rm = rowmask + ((size_t)(b * QN + i)) * 4;
            rm[0] = ((bj >> 6) == 0) ? (1ull << (bj & 63)) : 0ull;
            rm[1] = ((bj >> 6) == 1) ? (1ull << (bj & 63)) : 0ull;
            rm[2] = ((bj >> 6) == 2) ? (1ull << (bj & 63)) : 0ull;
            rm[3] = ((bj >> 6) == 3) ? (1ull << (bj & 63)) : 0ull;
            atomicAdd(&colcnt[b * GN + bj], 1);
            fixBj[e] = bj;
        }
    }
}

// ---------------- assign: only unmatched columns scan (rare), atomicMin u64 ----------------
__global__ __launch_bounds__(256) void k_assign(const float* __restrict__ costT,
                                                const unsigned char* __restrict__ pen,
                                                const int* __restrict__ colcnt,
                                                u64* __restrict__ amin) {
    const int j = threadIdx.x;
    const int b = blockIdx.y;
    const int i0 = blockIdx.x * 32;
    // Hoisted: only the (rare) unmatched columns do any memory work. Waves whose
    // 64 columns are all matched skip the loop entirely (execz).
    if (colcnt[b * GN + j] == 0) {
        u64 best = ~0ull;
        const unsigned char* pp = pen + (size_t)b * QN + i0;
        const float* C = costT + ((size_t)(b * QN) + i0) * GN + j;
        for (int r = 0; r < 32; r++) {
            if (!pp[r]) {                               // wave-uniform branch
                float v = C[(size_t)r * GN];
                u64 key = ((u64)fkey(v) << 32) | (unsigned int)(i0 + r);
                best = key < best ? key : best;
            }
        }
        if (best != ~0ull) atomicMin(&amin[b * GN + j], best);
    }
}

__global__ void k_assignfix(const u64* __restrict__ amin,
                            const int* __restrict__ colcnt,
                            int* __restrict__ assign, u64* __restrict__ rowmask) {
    const int col = blockIdx.x * 256 + threadIdx.x;
    const int b = col >> 8, j = col & 255;
    if (colcnt[col] != 0) { assign[col] = -1; return; }
    u64 key = amin[col];
    int r = (int)(unsigned int)(key & 0xFFFFFFFFull);
    assign[col] = r;
    atomicOr(&rowmask[((size_t)(b * QN + r)) * 4 + (j >> 6)], 1ull << (j & 63));
}

// ---------------- per-row outputs: selected, gt_idx ----------------
__global__ __launch_bounds__(256) void k_outrows(const u64* __restrict__ rowmask,
                                                 int* __restrict__ out) {
    int b = blockIdx.y;
    int i = blockIdx.x * 256 + threadIdx.x;
    const u64* rm = rowmask + ((size_t)(b * QN + i)) * 4;
    u64 w0 = rm[0], w1 = rm[1], w2 = rm[2], w3 = rm[3];
    int sel = (w0 | w1 | w2 | w3) ? 1 : 0;
    int g = 0;
    if (w0) g = __ffsll((long long)w0) - 1;
    else if (w1) g = 64 + __ffsll((long long)w1) - 1;
    else if (w2) g = 128 + __ffsll((long long)w2) - 1;
    else if (w3) g = 192 + __ffsll((long long)w3) - 1;
    out[(size_t)b * QN + i] = sel;
    out[(size_t)BN * QN + (size_t)b * QN + i] = g;
}

// ---------------- per-column output: matched_qidx (candidate-based) ----------------
__global__ __launch_bounds__(256) void k_outcols(const float* __restrict__ costT,
                                                 const u64* __restrict__ rowmask,
                                                 const int* __restrict__ assign,
                                                 const float* __restrict__ candcv,
                                                 const int* __restrict__ candci,
                                                 const int* __restrict__ dkArr,
                                                 const int* __restrict__ staleCount,
                                                 const int* __restrict__ staleList,
                                                 const int* __restrict__ fixBj,
                                                 int* __restrict__ out) {
    const int b = blockIdx.x;
    const int j = threadIdx.x;
    const int col = b * GN + j;
    int* o = out + (size_t)2 * BN * QN + col;
    int a = assign[col];
    if (a >= 0) { *o = a; return; }
    const u64 bit = 1ull << (j & 63);
    const int w = j >> 6;
    float best = FLT_MAX; int bi = INT_MAX;
    const int dk = dkArr[col];
    for (int k = 0; k < 5; k++) {
        if (k < dk) {
            int i = candci[(size_t)col * 5 + k];
            if (rowmask[((size_t)(b * QN + i)) * 4 + w] & bit) {
                float pv = candcv[(size_t)col * 5 + k] + 100000.0f;
                if (lexLessF(pv, i, best, bi)) { best = pv; bi = i; }
            }
        }
    }
    const int n = *staleCount;
    for (int e = 0; e < n; e++) {
        int pk = staleList[e];
        int eb = pk >> 12, ei = pk & 4095;
        if (eb == b && fixBj[e] == j) {
            float pv = costT[((size_t)(b * QN) + ei) * GN + j] + 100000.0f;
            if (lexLessF(pv, ei, best, bi)) { best = pv; bi = ei; }
        }
    }
    *o = (bi == INT_MAX) ? 0 : bi;
}

extern "C" void kernel_launch(void* const* d_in, const int* in_sizes, int n_in,
                              void* d_out, int out_size, void* d_ws, size_t ws_size,
                              hipStream_t stream) {
    const float* logits = (const float*)d_in[0];
    const float* pboxes = (const float*)d_in[1];
    const float* pposes = (const float*)d_in[2];
    const int* labels = (const int*)d_in[3];
    const float* gtb = (const float*)d_in[4];
    const float* gtt = (const float*)d_in[5];
    const float* gtr = (const float*)d_in[6];
    const float* img = (const float*)d_in[7];
    const float* imgt = (const float*)d_in[8];
    int* out = (int*)d_out;

    char* p = (char*)d_ws;
    float* costT = (float*)p;            p += (size_t)BN * QN * GN * 4;        // 64 MiB
    float* cclsT = (float*)p;            p += (size_t)BN * QN * CN * 4;        // 20 MiB
    float* rowp = (float*)p;             p += (size_t)BN * QN * 20 * 4;        // 5 MiB
    u64* pck = (u64*)p;                  p += (size_t)NPART * BN * GN * 5 * 8; // 20 MiB
    float* piv = (float*)p;              p += (size_t)NPART * BN * GN * 5 * 4; // 10 MiB
    u64* rowmask = (u64*)p;              size_t rb = (size_t)BN * QN * 4 * 8; p += rb;  // 2 MiB
    int* colcnt = (int*)p;               p += (size_t)BN * GN * 4;             // 16 KiB
    int* staleCount = (int*)p;           p += 64;
    int* staleList = (int*)p;            p += (size_t)BN * QN * 4;             // 256 KiB
    int* fixBj = (int*)p;                p += (size_t)BN * QN * 4;             // 256 KiB
    unsigned char* pen = (unsigned char*)p; p += (size_t)BN * QN;              // 64 KiB
    unsigned char* fgp = (unsigned char*)p; p += (size_t)BN * QN * 4;          // 256 KiB
    int* assign = (int*)p;               p += (size_t)BN * GN * 4;             // 16 KiB
    float* prmT = (float*)p;             p += (size_t)BN * NPRM * GN * 4;      // 376 KiB
    float* candcv = (float*)p;           p += (size_t)BN * GN * 5 * 4;         // 80 KiB
    int* candci = (int*)p;               p += (size_t)BN * GN * 5 * 4;         // 80 KiB
    int* dkArr = (int*)p;                p += (size_t)BN * GN * 4;             // 16 KiB
    u64* amin = (u64*)p;                 p += (size_t)BN * GN * 8;             // 32 KiB

    // zero rowmask + colcnt + staleCount (contiguous)
    int zn = (int)((rb + (size_t)BN * GN * 4 + 64) / 8);
    k_zero<<<(zn + 255) / 256, 256, 0, stream>>>(rowmask, zn);

    k_class<<<BN * 64, 256, 0, stream>>>(logits, gtb, gtt, gtr, imgt, cclsT, prmT);
    k_fg<<<dim3(QN / 256, BN, 4), 256, 0, stream>>>(gtb, pboxes, fgp);
    k_rows<<<dim3(QN / 256, BN), 256, 0, stream>>>(pboxes, pposes, img,
                                                   (const unsigned int*)fgp, rowp);
    k_main<<<BN * NPART, 256, 0, stream>>>(cclsT, labels, prmT, rowp, costT, pck, piv);
    k_dk<<<BN * GN / 4, 256, 0, stream>>>(pck, piv, candcv, candci, dkArr, rowmask, amin);
    k_stalepen<<<dim3(QN / 256, BN), 256, 0, stream>>>(rowmask, pen, colcnt, staleCount, staleList);
    k_stalefix<<<256, 256, 0, stream>>>(costT, rowmask, colcnt, staleCount, staleList, fixBj);
    k_assign<<<dim3(QN / 32, BN), 256, 0, stream>>>(costT, pen, colcnt, amin);
    k_assignfix<<<BN * GN / 256, 256, 0, stream>>>(amin, colcnt, assign, rowmask);
    k_outrows<<<dim3(QN / 256, BN), 256, 0, stream>>>(rowmask, out);
    k_outcols<<<BN, 256, 0, stream>>>(costT, rowmask, assign, candcv, candci, dkArr,
                                      staleCount, staleList, fixBj, out);
}

// Round 14
// 296.206 us; speedup vs baseline: 1.4072x; 1.1061x over previous
//
#include <hip/hip_runtime.h>
#include <cfloat>
#include <climits>
#include <math.h>

#define BN 16
#define QN 4096
#define GN 256
#define CN 80
#define NPART 128          // row parts in k_main (32 rows each)
#define RPP (QN / NPART)   // 32
#define NPRM 23            // column params

// k_pre sub-grid sizes
#define NZ_BLK 1033        // zero: ceil(264200/256)
#define NC_BLK 2048        // class: 16 b x 64 iblk x 2 half
#define NF_BLK 1024        // fg: 16 itile x 16 b x 4 part

typedef unsigned long long u64;

__device__ __forceinline__ bool lexLessF(float a, int ia, float b, int ib) {
    return (a < b) || (a == b && ia < ib);
}
// IEEE order-isomorphic u32 key (no NaNs in this data)
__device__ __forceinline__ unsigned int fkey(float f) {
    unsigned int b = __float_as_uint(f);
    return b ^ ((b >> 31) ? 0xFFFFFFFFu : 0x80000000u);
}
__device__ __forceinline__ float funkey(unsigned int k) {
    unsigned int b = k ^ ((k >> 31) ? 0x80000000u : 0xFFFFFFFFu);
    return __uint_as_float(b);
}

// ---------------- mega pre-kernel: zero | class | fg ----------------
__global__ __launch_bounds__(256) void k_pre(const float* __restrict__ logits,
                                             const float* __restrict__ gtb,
                                             const float* __restrict__ gtt,
                                             const float* __restrict__ gtr,
                                             const float* __restrict__ imgt,
                                             const float* __restrict__ pb,
                                             u64* __restrict__ zbase, int zn,
                                             float* __restrict__ cclsT,
                                             float* __restrict__ prmT,
                                             unsigned char* __restrict__ fgp) {
#pragma clang fp contract(off)
    const int blk = blockIdx.x;
    if (blk < NZ_BLK) {
        int i = blk * 256 + threadIdx.x;
        if (i < zn) zbase[i] = 0ull;
        return;
    }
    if (blk < NZ_BLK + NC_BLK) {
        // ---- class: ccls[b][i][c] (10 classes/thread, float2) + prm ----
        const int bid = blk - NZ_BLK;
        const int b = bid >> 7;
        const int rem = bid & 127;
        const int iblk = rem >> 1, h = rem & 1;
        const int lane = threadIdx.x & 63, cg = threadIdx.x >> 6;
        const int i = iblk * 64 + lane;
        const int c0 = h * 40 + cg * 10;
        const float* lrow = logits + ((size_t)(b * QN + i)) * CN + c0;
        float* orow = cclsT + ((size_t)(b * QN + i)) * CN + c0;
#pragma unroll
        for (int q = 0; q < 5; q++) {
            const float2 xv = *reinterpret_cast<const float2*>(lrow + q * 2);
            float xs[2] = {xv.x, xv.y};
            float os[2];
#pragma unroll
            for (int u = 0; u < 2; u++) {
                float x = xs[u];
                float e = (float)exp(-(double)x);
                float pr = 1.0f / (1.0f + e);
                float om = 1.0f - pr;
                float lneg = (float)log((double)(om + 1e-8f));
                float lpos = (float)log((double)(pr + 1e-8f));
                float neg = (0.75f * (pr * pr)) * (-lneg);
                float pos = (0.25f * (om * om)) * (-lpos);
                os[u] = pos - neg;
            }
            *reinterpret_cast<float2*>(orow + q * 2) = make_float2(os[0], os[1]);
        }
        if (rem == 0) {
            const int j = threadIdx.x;
            const float* g = gtb + ((size_t)(b * GN + j)) * 4;
            const float g0 = g[0], g1 = g[1], g2 = g[2], g3 = g[3];
            const float* it = imgt + ((size_t)(b * GN + j)) * 4;
            float* P = prmT + (size_t)b * NPRM * GN;
            P[0 * GN + j] = g0; P[1 * GN + j] = g1; P[2 * GN + j] = g2; P[3 * GN + j] = g3;
            P[4 * GN + j] = g0 / it[0]; P[5 * GN + j] = g1 / it[1];
            P[6 * GN + j] = g2 / it[2]; P[7 * GN + j] = g3 / it[3];
            P[8 * GN + j] = gtt[(b * GN + j) * 3 + 0]; P[9 * GN + j] = gtt[(b * GN + j) * 3 + 1];
            P[10 * GN + j] = gtt[(b * GN + j) * 3 + 2];
            P[11 * GN + j] = gtr[(b * GN + j) * 3 + 0]; P[12 * GN + j] = gtr[(b * GN + j) * 3 + 1];
            P[13 * GN + j] = gtr[(b * GN + j) * 3 + 2];
            P[14 * GN + j] = (g2 - g0) * (g3 - g1);   // ga
            float gcx = (g0 + g2) * 0.5f, gcy = (g1 + g3) * 0.5f;
            float gw = g2 - g0, gh = g3 - g1;
            float X0 = gcx - gw * 0.5f, Y0 = gcy - gh * 0.5f;
            float X1 = gcx + gw * 0.5f, Y1 = gcy + gh * 0.5f;
            float Wd = X1 - X0, Hd = Y1 - Y0;
            P[15 * GN + j] = X0; P[16 * GN + j] = Y0; P[17 * GN + j] = X1; P[18 * GN + j] = Y1;
            P[19 * GN + j] = gcx - 2.5f * Wd; P[20 * GN + j] = gcx + 2.5f * Wd;
            P[21 * GN + j] = gcy - 2.5f * Hd; P[22 * GN + j] = gcy + 2.5f * Hd;
        }
        return;
    }
    // ---- fg: 4-way j-split, float4 LDS ----
    {
        const int bid = blk - NZ_BLK - NC_BLK;       // itile(16) x b(16) x part(4)
        const int itile = bid >> 6;
        const int b = (bid >> 2) & 15;
        const int part = bid & 3;
        const int i = itile * 256 + threadIdx.x;
        __shared__ float4 sA[64], sB[64];
        if (threadIdx.x < 64) {
            const int j = part * 64 + threadIdx.x;
            const float* g = gtb + ((size_t)(b * GN + j)) * 4;
            float g0 = g[0], g1 = g[1], g2 = g[2], g3 = g[3];
            float gcx = (g0 + g2) * 0.5f, gcy = (g1 + g3) * 0.5f;
            float gw = g2 - g0, gh = g3 - g1;
            float x0 = gcx - gw * 0.5f, y0 = gcy - gh * 0.5f;
            float x1 = gcx + gw * 0.5f, y1 = gcy + gh * 0.5f;
            float w = x1 - x0, h2 = y1 - y0;
            sA[threadIdx.x] = make_float4(x0, y0, x1, y1);
            sB[threadIdx.x] = make_float4(gcx - 2.5f * w, gcx + 2.5f * w,
                                          gcy - 2.5f * h2, gcy + 2.5f * h2);
        }
        __syncthreads();
        const float4 bb = *reinterpret_cast<const float4*>(pb + ((size_t)(b * QN + i)) * 4);
        float ax = (bb.x + bb.z) * 0.5f, ay = (bb.y + bb.w) * 0.5f;
        bool anyib = false, anyic = false;
#pragma unroll 8
        for (int j = 0; j < 64; j++) {
            const float4 A = sA[j], B = sB[j];
            bool ib = (ax > A.x) && (ax < A.z) && (ay > A.y) && (ay < A.w);
            bool ic = (ax > B.x) && (ax < B.y) && (ay > B.z) && (ay < B.w);
            anyib |= ib; anyic |= ic;
        }
        fgp[((size_t)b * QN + i) * 4 + part] = (anyib || anyic) ? 1 : 0;
    }
}

// ---------------- fused cost + selection: column-per-thread, u64 keys ----------------
// Row-common table computed in-kernel into LDS (rows are block-exclusive).
__global__ __launch_bounds__(256) void k_main(
    const float* __restrict__ cclsT, const int* __restrict__ labels,
    const float* __restrict__ prmT,
    const float* __restrict__ pboxes, const float* __restrict__ pposes,
    const float* __restrict__ img, const unsigned int* __restrict__ fgw,
    float* __restrict__ costT,
    u64* __restrict__ pck, float* __restrict__ piv) {
#pragma clang fp contract(off)
    const int j = threadIdx.x;
    const int b = blockIdx.x >> 7;
    const int part = blockIdx.x & 127;
    const int i0 = part * RPP;

    __shared__ float4 Rsh[RPP][5];
    if (threadIdx.x < RPP) {
        const int i = i0 + threadIdx.x;
        const float im0 = img[b * 4 + 0], im1 = img[b * 4 + 1];
        const float im2 = img[b * 4 + 2], im3 = img[b * 4 + 3];
        const float4 bx = *reinterpret_cast<const float4*>(pboxes + ((size_t)(b * QN + i)) * 4);
        const float b0 = bx.x, b1 = bx.y, b2 = bx.z, b3 = bx.w;
        const float2* pp2 = reinterpret_cast<const float2*>(pposes + ((size_t)(b * QN + i)) * 6);
        const float2 q0 = pp2[0], q1 = pp2[1], q2 = pp2[2];
        const float fgadd = fgw[(size_t)b * QN + i] ? 0.0f : 10000.0f;
        const float bn0 = b0 / im0, bn1 = b1 / im1, bn2 = b2 / im2, bn3 = b3 / im3;
        const float a1 = (b2 - b0) * (b3 - b1);
        const float ax = (b0 + b2) * 0.5f, ay = (b1 + b3) * 0.5f;
        Rsh[threadIdx.x][0] = make_float4(b0, b1, b2, b3);
        Rsh[threadIdx.x][1] = make_float4(bn0, bn1, bn2, bn3);
        Rsh[threadIdx.x][2] = make_float4(ax, ay, a1, fgadd);
        Rsh[threadIdx.x][3] = make_float4(q0.x, q0.y, q1.x, q1.y);
        Rsh[threadIdx.x][4] = make_float4(q2.x, q2.y, 0.0f, 0.0f);
    }

    const float* P = prmT + (size_t)b * NPRM * GN;
    const float g0 = P[0 * GN + j], g1 = P[1 * GN + j], g2 = P[2 * GN + j], g3 = P[3 * GN + j];
    const float gn0 = P[4 * GN + j], gn1 = P[5 * GN + j], gn2 = P[6 * GN + j], gn3 = P[7 * GN + j];
    const float t0 = P[8 * GN + j], t1 = P[9 * GN + j], t2 = P[10 * GN + j];
    const float r0 = P[11 * GN + j], r1 = P[12 * GN + j], r2 = P[13 * GN + j];
    const float ga = P[14 * GN + j];
    const float X0 = P[15 * GN + j], Y0 = P[16 * GN + j], X1 = P[17 * GN + j], Y1 = P[18 * GN + j];
    const float LOX = P[19 * GN + j], HIX = P[20 * GN + j], LOY = P[21 * GN + j], HIY = P[22 * GN + j];
    const int lab = labels[b * GN + j];

    const float* CB = cclsT + ((size_t)(b * QN) + i0) * CN;     // uniform base + lab
    float* CT = costT + ((size_t)(b * QN) + i0) * GN + j;

    u64 ck[5]; float iv[5];
#pragma unroll
    for (int k = 0; k < 5; k++) { ck[k] = ~0ull; iv[k] = -1.0f; }

    __syncthreads();

    for (int r = 0; r < RPP; r++) {
        const int i = i0 + r;
        const float4 R0 = Rsh[r][0];
        const float4 R1 = Rsh[r][1];
        const float4 R2 = Rsh[r][2];
        const float4 R3 = Rsh[r][3];
        const float4 R4 = Rsh[r][4];
        const float b0 = R0.x, b1 = R0.y, b2 = R0.z, b3 = R0.w;
        const float bn0 = R1.x, bn1 = R1.y, bn2 = R1.z, bn3 = R1.w;
        const float ax = R2.x, ay = R2.y, a1 = R2.z, fgadd = R2.w;
        const float p0 = R3.x, p1 = R3.y, p2 = R3.z, p3 = R3.w;
        const float p4 = R4.x, p5 = R4.y;
        const float cc = CB[r * CN + lab];

        // iou / giou (f32, reference op order)
        float ltx = fmaxf(b0, g0), lty = fmaxf(b1, g1);
        float rbx = fminf(b2, g2), rby = fminf(b3, g3);
        float w = fmaxf(rbx - ltx, 0.0f), h = fmaxf(rby - lty, 0.0f);
        float inter = w * h;
        float uni = (a1 + ga) - inter;
        float iou = inter / uni;
        float eltx = fminf(b0, g0), elty = fminf(b1, g1);
        float erbx = fmaxf(b2, g2), erby = fmaxf(b3, g3);
        float ew = fmaxf(erbx - eltx, 0.0f), eh = fmaxf(erby - elty, 0.0f);
        float earea = ew * eh;
        float giou = iou - (earea - uni) / earea;

        // normalized bbox L1 (sequential f32)
        float cb = fabsf(bn0 - gn0);
        cb = cb + fabsf(bn1 - gn1);
        cb = cb + fabsf(bn2 - gn2);
        cb = cb + fabsf(bn3 - gn3);
        // pose L1
        float ct = fabsf(p0 - t0); ct = ct + fabsf(p1 - t1); ct = ct + fabsf(p2 - t2);
        float cr = fabsf(p3 - r0); cr = cr + fabsf(p4 - r1); cr = cr + fabsf(p5 - r2);
        // both
        bool ib = (ax > X0) && (ax < X1) && (ay > Y0) && (ay < Y1);
        bool ic = (ax > LOX) && (ax < HIX) && (ay > LOY) && (ay < HIY);
        bool nb = !(ib && ic);

        float d = 5.0f * cb;
        d = d + 2.0f * cc;
        d = d + 2.0f * (-giou);
        d = d + (nb ? 100.0f : 0.0f);
        d = d + ct;
        d = d + cr;
        d = d + fgadd;

        CT[(size_t)r * GN] = d;

        // bottom-5 via u64 key cascade (order-isomorphic to (cost,i) lex)
        u64 key = ((u64)fkey(d) << 32) | (unsigned int)i;
        if (key < ck[4]) {
#pragma unroll
            for (int k = 0; k < 5; k++) {
                u64 mn = key < ck[k] ? key : ck[k];
                u64 mx = key < ck[k] ? ck[k] : key;
                ck[k] = mn; key = mx;
            }
        }
        // top-5 iou via max/min network
        if (iou > iv[4]) {
            float fv = iou;
#pragma unroll
            for (int k = 0; k < 5; k++) {
                float mx = fmaxf(fv, iv[k]);
                fv = fminf(fv, iv[k]);
                iv[k] = mx;
            }
        }
    }

    const int col = b * GN + j;
    const size_t base = ((size_t)part * (BN * GN) + col) * 5;
#pragma unroll
    for (int k = 0; k < 5; k++) { pck[base + k] = ck[k]; piv[base + k] = iv[k]; }
}

// ---------------- merge parts (wave butterfly), dk, rowmask, amin init ----------------
__global__ __launch_bounds__(256) void k_dk(const u64* __restrict__ pck,
                                            const float* __restrict__ piv,
                                            float* __restrict__ candcv, int* __restrict__ candci,
                                            int* __restrict__ dkArr, u64* __restrict__ rowmask,
                                            u64* __restrict__ amin) {
#pragma clang fp contract(off)
    const int lane = threadIdx.x & 63;
    const int colIdx = blockIdx.x * 4 + (threadIdx.x >> 6);   // 4 waves/block
    const int b = colIdx >> 8, j = colIdx & 255;
    const size_t base0 = ((size_t)lane * (BN * GN) + colIdx) * 5;
    const size_t base1 = ((size_t)(lane + 64) * (BN * GN) + colIdx) * 5;
    u64 rv[5]; float fr[5];
#pragma unroll
    for (int k = 0; k < 5; k++) { rv[k] = pck[base0 + k]; fr[k] = piv[base0 + k]; }
#pragma unroll
    for (int m = 0; m < 5; m++) {
        u64 key = pck[base1 + m];
        if (key < rv[4]) {
#pragma unroll
            for (int k = 0; k < 5; k++) {
                u64 mn = key < rv[k] ? key : rv[k];
                u64 mx = key < rv[k] ? rv[k] : key;
                rv[k] = mn; key = mx;
            }
        }
        float fv = piv[base1 + m];
        if (fv > fr[4]) {
#pragma unroll
            for (int k = 0; k < 5; k++) {
                float mx = fmaxf(fv, fr[k]);
                fv = fminf(fv, fr[k]);
                fr[k] = mx;
            }
        }
    }
    for (int off = 1; off < 64; off <<= 1) {
        u64 ov[5]; float of[5];
#pragma unroll
        for (int m = 0; m < 5; m++) {
            ov[m] = __shfl_xor(rv[m], off, 64);
            of[m] = __shfl_xor(fr[m], off, 64);
        }
#pragma unroll
        for (int m = 0; m < 5; m++) {
            u64 key = ov[m];
            if (key < rv[4]) {
#pragma unroll
                for (int k = 0; k < 5; k++) {
                    u64 mn = key < rv[k] ? key : rv[k];
                    u64 mx = key < rv[k] ? rv[k] : key;
                    rv[k] = mn; key = mx;
                }
            }
            float fv = of[m];
            if (fv > fr[4]) {
#pragma unroll
                for (int k = 0; k < 5; k++) {
                    float mx = fmaxf(fv, fr[k]);
                    fv = fminf(fv, fr[k]);
                    fr[k] = mx;
                }
            }
        }
    }

    if (lane == 0) {
        float sum = ((((fr[0] + fr[1]) + fr[2]) + fr[3]) + fr[4]);  // desc order, sequential
        int dk = (int)sum;
        if (dk < 1) dk = 1;
        if (dk > 5) dk = 5;
        dkArr[colIdx] = dk;
        amin[colIdx] = ~0ull;
#pragma unroll
        for (int k = 0; k < 5; k++) {
            candcv[(size_t)colIdx * 5 + k] = funkey((unsigned int)(rv[k] >> 32));
            candci[(size_t)colIdx * 5 + k] = (int)(unsigned int)(rv[k] & 0xFFFFFFFFull);
        }
        for (int k = 0; k < dk; k++) {
            int i = (int)(unsigned int)(rv[k] & 0xFFFFFFFFull);
            atomicOr(&rowmask[((size_t)(b * QN + i)) * 4 + (j >> 6)], 1ull << (j & 63));
        }
    }
}

// ---------------- stale detect + pen + colcnt ----------------
__global__ __launch_bounds__(256) void k_stalepen(u64* __restrict__ rowmask,
                                                  unsigned char* __restrict__ pen,
                                                  int* __restrict__ colcnt,
                                                  int* __restrict__ staleCount,
                                                  int* __restrict__ staleList) {
    int b = blockIdx.y;
    int i = blockIdx.x * 256 + threadIdx.x;
    u64* rm = rowmask + ((size_t)(b * QN + i)) * 4;
    u64 w0 = rm[0], w1 = rm[1], w2 = rm[2], w3 = rm[3];
    int cnt = __popcll(w0) + __popcll(w1) + __popcll(w2) + __popcll(w3);
    pen[(size_t)b * QN + i] = (cnt > 0) ? 1 : 0;
    if (cnt > 1) {
        int idx = atomicAdd(staleCount, 1);
        staleList[idx] = (b << 12) | i;
    } else if (cnt == 1) {
        u64 w; int base;
        if (w0) { w = w0; base = 0; }
        else if (w1) { w = w1; base = 64; }
        else if (w2) { w = w2; base = 128; }
        else { w = w3; base = 192; }
        int j = base + (__ffsll((long long)w) - 1);
        atomicAdd(&colcnt[b * GN + j], 1);
    }
}

// ---------------- fused: stalefix (blocks 0..255) | assign (rest) ----------------
// Safe fusion: assign's spurious amin writes for columns that stalefix marks
// matched are discarded by k_assignfix's post-fix colcnt read; pen is not
// modified by stalefix.
__global__ __launch_bounds__(256) void k_fix(const float* __restrict__ costT,
                                             u64* __restrict__ rowmask,
                                             int* __restrict__ colcnt,
                                             const int* __restrict__ staleCount,
                                             const int* __restrict__ staleList,
                                             int* __restrict__ fixBj,
                                             const unsigned char* __restrict__ pen,
                                             u64* __restrict__ amin) {
    if (blockIdx.x < 256) {
        // ---- stalefix ----
        int gtid = blockIdx.x * blockDim.x + threadIdx.x;
        int wid = gtid >> 6;
        int lane = threadIdx.x & 63;
        int nw = (256 * 256) >> 6;
        int n = *staleCount;
        for (int e = wid; e < n; e += nw) {
            int pk = staleList[e];
            int b = pk >> 12, i = pk & 4095;
            const float* cb = costT + ((size_t)(b * QN) + i) * GN;   // contiguous row
            float best = FLT_MAX; int bj = GN;
            for (int k = 0; k < GN; k += 64) {
                int j = k + lane;
                float v = cb[j];
                if (lexLessF(v, j, best, bj)) { best = v; bj = j; }
            }
            for (int off = 32; off > 0; off >>= 1) {
                float ov = __shfl_down(best, off, 64);
                int oj = __shfl_down(bj, off, 64);
                if (lexLessF(ov, oj, best, bj)) { best = ov; bj = oj; }
            }
            if (lane == 0) {
                u64* rm = rowmask + ((size_t)(b * QN + i)) * 4;
                rm[0] = ((bj >> 6) == 0) ? (1ull << (bj & 63)) : 0ull;
                rm[1] = ((bj >> 6) == 1) ? (1ull << (bj & 63)) : 0ull;
                rm[2] = ((bj >> 6) == 2) ? (1ull << (bj & 63)) : 0ull;
                rm[3] = ((bj >> 6) == 3) ? (1ull << (bj & 63)) : 0ull;
                atomicAdd(&colcnt[b * GN + bj], 1);
                fixBj[e] = bj;
            }
        }
    } else {
        // ---- assign: only unmatched columns scan ----
        const int bid = blockIdx.x - 256;          // 128 iblk x 16 b
        const int b = bid >> 7;
        const int i0 = (bid & 127) * 32;
        const int j = threadIdx.x;
        if (colcnt[b * GN + j] == 0) {
            u64 best = ~0ull;
            const unsigned char* pp = pen + (size_t)b * QN + i0;
            const float* C = costT + ((size_t)(b * QN) + i0) * GN + j;
            for (int r = 0; r < 32; r++) {
                if (!pp[r]) {                       // wave-uniform branch
                    float v = C[(size_t)r * GN];
                    u64 key = ((u64)fkey(v) << 32) | (unsigned int)(i0 + r);
                    best = key < best ? key : best;
                }
            }
            if (best != ~0ull) atomicMin(&amin[b * GN + j], best);
        }
    }
}

__global__ void k_assignfix(const u64* __restrict__ amin,
                            const int* __restrict__ colcnt,
                            int* __restrict__ assign, u64* __restrict__ rowmask) {
    const int col = blockIdx.x * 256 + threadIdx.x;
    const int b = col >> 8, j = col & 255;
    if (colcnt[col] != 0) { assign[col] = -1; return; }
    u64 key = amin[col];
    int r = (int)(unsigned int)(key & 0xFFFFFFFFull);
    assign[col] = r;
    atomicOr(&rowmask[((size_t)(b * QN + r)) * 4 + (j >> 6)], 1ull << (j & 63));
}

// ---------------- fused outputs: outrows (blocks 0..255) | outcols (rest) ----------------
__global__ __launch_bounds__(256) void k_out(const float* __restrict__ costT,
                                             const u64* __restrict__ rowmask,
                                             const int* __restrict__ assign,
                                             const float* __restrict__ candcv,
                                             const int* __restrict__ candci,
                                             const int* __restrict__ dkArr,
                                             const int* __restrict__ staleCount,
                                             const int* __restrict__ staleList,
                                             const int* __restrict__ fixBj,
                                             int* __restrict__ out) {
    if (blockIdx.x < 256) {
        // ---- outrows ----
        const int b = blockIdx.x >> 4;
        const int i = (blockIdx.x & 15) * 256 + threadIdx.x;
        const u64* rm = rowmask + ((size_t)(b * QN + i)) * 4;
        u64 w0 = rm[0], w1 = rm[1], w2 = rm[2], w3 = rm[3];
        int sel = (w0 | w1 | w2 | w3) ? 1 : 0;
        int g = 0;
        if (w0) g = __ffsll((long long)w0) - 1;
        else if (w1) g = 64 + __ffsll((long long)w1) - 1;
        else if (w2) g = 128 + __ffsll((long long)w2) - 1;
        else if (w3) g = 192 + __ffsll((long long)w3) - 1;
        out[(size_t)b * QN + i] = sel;
        out[(size_t)BN * QN + (size_t)b * QN + i] = g;
        return;
    }
    // ---- outcols ----
    const int b = blockIdx.x - 256;
    const int j = threadIdx.x;
    const int col = b * GN + j;
    int* o = out + (size_t)2 * BN * QN + col;
    int a = assign[col];
    if (a >= 0) { *o = a; return; }
    const u64 bit = 1ull << (j & 63);
    const int w = j >> 6;
    float best = FLT_MAX; int bi = INT_MAX;
    const int dk = dkArr[col];
    for (int k = 0; k < 5; k++) {
        if (k < dk) {
            int i = candci[(size_t)col * 5 + k];
            if (rowmask[((size_t)(b * QN + i)) * 4 + w] & bit) {
                float pv = candcv[(size_t)col * 5 + k] + 100000.0f;
                if (lexLessF(pv, i, best, bi)) { best = pv; bi = i; }
            }
        }
    }
    const int n = *staleCount;
    for (int e = 0; e < n; e++) {
        int pk = staleList[e];
        int eb = pk >> 12, ei = pk & 4095;
        if (eb == b && fixBj[e] == j) {
            float pv = costT[((size_t)(b * QN) + ei) * GN + j] + 100000.0f;
            if (lexLessF(pv, ei, best, bi)) { best = pv; bi = ei; }
        }
    }
    *o = (bi == INT_MAX) ? 0 : bi;
}

extern "C" void kernel_launch(void* const* d_in, const int* in_sizes, int n_in,
                              void* d_out, int out_size, void* d_ws, size_t ws_size,
                              hipStream_t stream) {
    const float* logits = (const float*)d_in[0];
    const float* pboxes = (const float*)d_in[1];
    const float* pposes = (const float*)d_in[2];
    const int* labels = (const int*)d_in[3];
    const float* gtb = (const float*)d_in[4];
    const float* gtt = (const float*)d_in[5];
    const float* gtr = (const float*)d_in[6];
    const float* img = (const float*)d_in[7];
    const float* imgt = (const float*)d_in[8];
    int* out = (int*)d_out;

    char* p = (char*)d_ws;
    float* costT = (float*)p;            p += (size_t)BN * QN * GN * 4;        // 64 MiB
    float* cclsT = (float*)p;            p += (size_t)BN * QN * CN * 4;        // 20 MiB
    u64* pck = (u64*)p;                  p += (size_t)NPART * BN * GN * 5 * 8; // 20 MiB
    float* piv = (float*)p;              p += (size_t)NPART * BN * GN * 5 * 4; // 10 MiB
    u64* rowmask = (u64*)p;              size_t rb = (size_t)BN * QN * 4 * 8; p += rb;  // 2 MiB
    int* colcnt = (int*)p;               p += (size_t)BN * GN * 4;             // 16 KiB
    int* staleCount = (int*)p;           p += 64;
    int* staleList = (int*)p;            p += (size_t)BN * QN * 4;             // 256 KiB
    int* fixBj = (int*)p;                p += (size_t)BN * QN * 4;             // 256 KiB
    unsigned char* pen = (unsigned char*)p; p += (size_t)BN * QN;              // 64 KiB
    unsigned char* fgp = (unsigned char*)p; p += (size_t)BN * QN * 4;          // 256 KiB
    int* assign = (int*)p;               p += (size_t)BN * GN * 4;             // 16 KiB
    float* prmT = (float*)p;             p += (size_t)BN * NPRM * GN * 4;      // 376 KiB
    float* candcv = (float*)p;           p += (size_t)BN * GN * 5 * 4;         // 80 KiB
    int* candci = (int*)p;               p += (size_t)BN * GN * 5 * 4;         // 80 KiB
    int* dkArr = (int*)p;                p += (size_t)BN * GN * 4;             // 16 KiB
    u64* amin = (u64*)p;                 p += (size_t)BN * GN * 8;             // 32 KiB

    // zero region: rowmask + colcnt + staleCount (contiguous)
    int zn = (int)((rb + (size_t)BN * GN * 4 + 64) / 8);   // = 264200

    k_pre<<<NZ_BLK + NC_BLK + NF_BLK, 256, 0, stream>>>(logits, gtb, gtt, gtr, imgt, pboxes,
                                                        rowmask, zn, cclsT, prmT, fgp);
    k_main<<<BN * NPART, 256, 0, stream>>>(cclsT, labels, prmT, pboxes, pposes, img,
                                           (const unsigned int*)fgp, costT, pck, piv);
    k_dk<<<BN * GN / 4, 256, 0, stream>>>(pck, piv, candcv, candci, dkArr, rowmask, amin);
    k_stalepen<<<dim3(QN / 256, BN), 256, 0, stream>>>(rowmask, pen, colcnt, staleCount, staleList);
    k_fix<<<256 + BN * 128, 256, 0, stream>>>(costT, rowmask, colcnt, staleCount, staleList,
                                              fixBj, pen, amin);
    k_assignfix<<<BN * GN / 256, 256, 0, stream>>>(amin, colcnt, assign, rowmask);
    k_out<<<256 + BN, 256, 0, stream>>>(costT, rowmask, assign, candcv, candci, dkArr,
                                        staleCount, staleList, fixBj, out);
}